// Round 7
// baseline (164.557 us; speedup 1.0000x reference)
//
#include <hip/hip_runtime.h>

typedef unsigned short u16;
typedef _Float16 f16;

using half8   = __attribute__((ext_vector_type(8))) _Float16;
using f32x4   = __attribute__((ext_vector_type(4))) float;
using ushort8 = __attribute__((ext_vector_type(8))) unsigned short;
using us4     = __attribute__((ext_vector_type(4))) unsigned short;
using float4v = __attribute__((ext_vector_type(4))) float;

#define B_  8
#define S_  2048
#define D_  512
#define BK  32

__device__ __forceinline__ u16 f2h(float f) {
  f16 h = (f16)f;
  u16 u;
  __builtin_memcpy(&u, &h, 2);
  return u;
}

__device__ __forceinline__ float h2f(u16 h) {
  f16 x;
  __builtin_memcpy(&x, &h, 2);
  return (float)x;
}

__device__ __forceinline__ void stage16(const void* g, void* l) {
  __builtin_amdgcn_global_load_lds((const __attribute__((address_space(1))) void*)g,
                                   (__attribute__((address_space(3))) void*)l,
                                   16, 0, 0);
}

// XCD-aware bijective remap (all grids have nwg % 8 == 0).
__device__ __forceinline__ void xcd_remap(int& bx, int& by, int& bz) {
  const int lin = ((int)blockIdx.z * (int)gridDim.y + (int)blockIdx.y) * (int)gridDim.x
                  + (int)blockIdx.x;
  const int nwg = (int)gridDim.x * (int)gridDim.y * (int)gridDim.z;
  const int swz = (lin & 7) * (nwg >> 3) + (lin >> 3);
  bx = swz % (int)gridDim.x;
  const int tmp = swz / (int)gridDim.x;
  by = tmp % (int)gridDim.y;
  bz = tmp / (int)gridDim.y;
}

// C[BM x 256] = A[BM x K] * B[256 x K]^T, fp16 in, fp32 accum. BM = M_REP*32.
// 512 threads = 8 waves, 2M x 4N; per-wave output (M_REP*16) x 64.
// Same proven pipeline as the 128^2 version: 4 LDS buffers, depth-3 prefetch,
// counted vmcnt (steady 2L, L = loads/thread/tile), one raw s_barrier per
// iter, wait-own-vmcnt BEFORE barrier; iter u reads buf u&3, stages tile u+3
// into buf (u+3)&3 = (u-1)&3 whose readers finished before this barrier.
// LDS per-matrix image: paired rows [rows/2][8 slots x 16B], global (r, g) ->
// LDS row r>>1, slot (((r&1)<<2)|g) ^ ((r>>1)&7). Bijective, <=2-way bank
// alias on fragment reads (free), gload_lds dest linear + global source
// pre-swizzled (both-sides rule). PMC-verified conflict-free (rounds 4-6).
// mfma_f32_16x16x32_f16 frags: A/B row|col = lane&15, k = (lane>>4)*8 + j;
//                              C/D col = lane&15, row = (lane>>4)*4 + reg.
template<int M_REP>
__device__ __forceinline__ void gemm_core256(const u16* __restrict__ A,
                                             const u16* __restrict__ B,
                                             int K, int m0, int n0,
                                             u16* lds, f32x4 acc[M_REP][4]) {
  constexpr int BM      = M_REP * 32;
  constexpr int A_ELEMS = BM * 32;          // elems per A image
  constexpr int BUFE    = (BM + 256) * 32;  // elems per buffer (A+B)
  constexpr int SA      = BM / 128;         // A sweeps per tile (1 or 2)

  const int tid  = threadIdx.x;
  const int lane = tid & 63;
  const int wave = tid >> 6;
  const int wr = wave >> 2, wc = wave & 3;
  const int fr   = lane & 15;
  const int fgrp = lane >> 4;

  // staging source decode: sweep s covers bytes p = tid*16 + s*8192 of the image
  int sra[2], sca[2], srb[2], scb[2];
  #pragma unroll
  for (int s = 0; s < 2; ++s) {
    const int p    = tid * 16 + s * 8192;
    const int R    = p >> 7;
    const int slot = (p >> 4) & 7;
    const int s0   = slot ^ (R & 7);
    sra[s] = srb[s] = 2 * R + (s0 >> 2);
    sca[s] = scb[s] = (s0 & 3) * 8;
  }

  // fragment read byte-offsets within an image
  int offA[M_REP], offB[4];
  #pragma unroll
  for (int m = 0; m < M_REP; ++m) {
    const int ra = wr * (M_REP * 16) + m * 16 + fr;
    const int Ra = ra >> 1;
    offA[m] = Ra * 128 + (((((ra & 1) << 2) | fgrp) ^ (Ra & 7)) << 4);
  }
  #pragma unroll
  for (int n = 0; n < 4; ++n) {
    const int rb = wc * 64 + n * 16 + fr;
    const int Rb = rb >> 1;
    offB[n] = Rb * 128 + (((((rb & 1) << 2) | fgrp) ^ (Rb & 7)) << 4);
  }

  const f32x4 vzero = {0.f, 0.f, 0.f, 0.f};
  #pragma unroll
  for (int m = 0; m < M_REP; ++m)
    #pragma unroll
    for (int n = 0; n < 4; ++n)
      acc[m][n] = vzero;

  const int T = K / BK;

  auto STAGE = [&](int t, u16* buf) {
    #pragma unroll
    for (int s = 0; s < SA; ++s)
      stage16(A + (size_t)(m0 + sra[s]) * K + t * BK + sca[s],
              buf + s * 4096 + wave * 512);
    #pragma unroll
    for (int s = 0; s < 2; ++s)
      stage16(B + (size_t)(n0 + srb[s]) * K + t * BK + scb[s],
              buf + A_ELEMS + s * 4096 + wave * 512);
  };

  // prologue: tiles 0,1,2 in flight (3L loads/thread)
  STAGE(0, lds);
  STAGE(1, lds + BUFE);
  STAGE(2, lds + 2 * BUFE);

  int t = 0;
#define GEMM_ITER(WN)                                                            \
  {                                                                              \
    asm volatile("s_waitcnt vmcnt(" #WN ")\n\ts_barrier" ::: "memory");          \
    const u16* buf = lds + (t & 3) * BUFE;                                       \
    half8 a[M_REP], b[4];                                                        \
    _Pragma("unroll")                                                            \
    for (int m = 0; m < M_REP; ++m)                                              \
      a[m] = *(const half8*)((const char*)buf + offA[m]);                        \
    _Pragma("unroll")                                                            \
    for (int n = 0; n < 4; ++n)                                                  \
      b[n] = *(const half8*)((const char*)(buf + A_ELEMS) + offB[n]);            \
    if (t + 3 < T) STAGE(t + 3, lds + ((t + 3) & 3) * BUFE);                     \
    __builtin_amdgcn_s_setprio(1);                                               \
    _Pragma("unroll")                                                            \
    for (int m = 0; m < M_REP; ++m)                                              \
      _Pragma("unroll")                                                          \
      for (int n = 0; n < 4; ++n)                                                \
        acc[m][n] = __builtin_amdgcn_mfma_f32_16x16x32_f16(a[m], b[n],           \
                                                           acc[m][n], 0, 0, 0); \
    __builtin_amdgcn_s_setprio(0);                                               \
  }

  if constexpr (SA == 2) {  // L=4: steady vmcnt(8), then 4, then 0
    for (; t < T - 2; ++t) GEMM_ITER(8)
    GEMM_ITER(4); ++t;
    GEMM_ITER(0);
  } else {                  // L=3: steady vmcnt(6), then 3, then 0
    for (; t < T - 2; ++t) GEMM_ITER(6)
    GEMM_ITER(3); ++t;
    GEMM_ITER(0);
  }
#undef GEMM_ITER
}

// ---------------- projections (256x256): Q/K fp16 store, V transposed [b][d][s] ----------------
__global__ __launch_bounds__(512) void proj_kernel(
    const u16* __restrict__ xh, const u16* __restrict__ Wh,
    const float* __restrict__ bq, const float* __restrict__ bk, const float* __restrict__ bv,
    u16* __restrict__ Qb, u16* __restrict__ Kb, u16* __restrict__ Vt) {
  __shared__ __align__(16) u16 lds[4 * (256 + 256) * 32];  // 128 KB
  int bx, by, bz;
  xcd_remap(bx, by, bz);
  const int z  = bz;
  const int m0 = by * 256;
  const int n0 = bx * 256;
  const u16* W = Wh + (size_t)z * D_ * D_;
  const float* bias = (z == 0) ? bq : (z == 1) ? bk : bv;
  f32x4 acc[8][4];
  gemm_core256<8>(xh, W, D_, m0, n0, lds, acc);

  const int lane = threadIdx.x & 63;
  const int wave = threadIdx.x >> 6;
  const int wr = wave >> 2, wc = wave & 3;
  #pragma unroll
  for (int m = 0; m < 8; ++m) {
    const int gr0 = m0 + wr * 128 + m * 16 + ((lane >> 4) << 2);
    #pragma unroll
    for (int n = 0; n < 4; ++n) {
      const int gc = n0 + wc * 64 + n * 16 + (lane & 15);
      const float bb = bias[gc];
      if (z < 2) {
        u16* O = z ? Kb : Qb;
        #pragma unroll
        for (int r = 0; r < 4; ++r)
          O[(size_t)(gr0 + r) * D_ + gc] = f2h(acc[m][n][r] + bb);
      } else {
        const int bidx = gr0 >> 11;      // 2048 rows/batch; 256-tiles never straddle
        const int s    = gr0 & 2047;
        us4 p;
        #pragma unroll
        for (int r = 0; r < 4; ++r) p[r] = f2h(acc[m][n][r] + bb);
        *(us4*)(Vt + ((size_t)bidx * D_ + gc) * S_ + s) = p;
      }
    }
  }
}

// ---------------- QK^T (256x256) -> E fp16 ----------------
__global__ __launch_bounds__(512) void qk_kernel(
    const u16* __restrict__ Qb, const u16* __restrict__ Kb, u16* __restrict__ E,
    size_t sA, size_t sE) {
  __shared__ __align__(16) u16 lds[4 * (256 + 256) * 32];  // 128 KB
  int bx, by, bz;
  xcd_remap(bx, by, bz);
  const int z  = bz;
  const int m0 = by * 256;
  const int n0 = bx * 256;
  f32x4 acc[8][4];
  gemm_core256<8>(Qb + (size_t)z * sA, Kb + (size_t)z * sA, D_, m0, n0, lds, acc);

  u16* Eb = E + (size_t)z * sE;
  const int lane = threadIdx.x & 63;
  const int wave = threadIdx.x >> 6;
  const int wr = wave >> 2, wc = wave & 3;
  #pragma unroll
  for (int m = 0; m < 8; ++m) {
    const int gr0 = m0 + wr * 128 + m * 16 + ((lane >> 4) << 2);
    #pragma unroll
    for (int n = 0; n < 4; ++n) {
      const int gc = n0 + wc * 64 + n * 16 + (lane & 15);
      #pragma unroll
      for (int r = 0; r < 4; ++r)
        Eb[(size_t)(gr0 + r) * S_ + gc] = f2h(acc[m][n][r]);
    }
  }
}

// ---------------- row softmax, in place fp16 -> fp16 ----------------
__global__ __launch_bounds__(256) void softmax_kernel(u16* __restrict__ E) {
  const int row  = blockIdx.x * 4 + (threadIdx.x >> 6);
  const int lane = threadIdx.x & 63;
  u16* R = E + (size_t)row * S_;
  float e[32];
  #pragma unroll
  for (int i = 0; i < 4; ++i) {
    ushort8 v = *(const ushort8*)(R + i * 512 + lane * 8);
    #pragma unroll
    for (int j = 0; j < 8; ++j) e[i * 8 + j] = h2f(v[j]);
  }
  float m = e[0];
  #pragma unroll
  for (int i = 1; i < 32; ++i) m = fmaxf(m, e[i]);
  for (int off = 32; off > 0; off >>= 1) m = fmaxf(m, __shfl_xor(m, off, 64));
  float s = 0.f;
  #pragma unroll
  for (int i = 0; i < 32; ++i) { e[i] = __expf(e[i] - m); s += e[i]; }
  for (int off = 32; off > 0; off >>= 1) s += __shfl_xor(s, off, 64);
  const float inv = 1.f / s;
  #pragma unroll
  for (int i = 0; i < 4; ++i) {
    ushort8 v;
    #pragma unroll
    for (int j = 0; j < 8; ++j) v[j] = f2h(e[i * 8 + j] * inv);
    *(ushort8*)(R + i * 512 + lane * 8) = v;
  }
}

// ---------------- PV (128x256) -> fp32 out ----------------
__global__ __launch_bounds__(512) void pv_kernel(
    const u16* __restrict__ P, const u16* __restrict__ Vt, float* __restrict__ out,
    size_t sP, size_t sV, size_t sO) {
  __shared__ __align__(16) u16 lds[4 * (128 + 256) * 32];  // 96 KB
  int bx, by, bz;
  xcd_remap(bx, by, bz);
  const int z  = bz;
  const int m0 = by * 128;
  const int n0 = bx * 256;
  f32x4 acc[4][4];
  gemm_core256<4>(P + (size_t)z * sP, Vt + (size_t)z * sV, S_, m0, n0, lds, acc);

  float* Ob = out + (size_t)z * sO;
  const int lane = threadIdx.x & 63;
  const int wave = threadIdx.x >> 6;
  const int wr = wave >> 2, wc = wave & 3;
  #pragma unroll
  for (int m = 0; m < 4; ++m) {
    const int gr0 = m0 + wr * 64 + m * 16 + ((lane >> 4) << 2);
    #pragma unroll
    for (int n = 0; n < 4; ++n) {
      const int gc = n0 + wc * 64 + n * 16 + (lane & 15);
      #pragma unroll
      for (int r = 0; r < 4; ++r)
        Ob[(size_t)(gr0 + r) * D_ + gc] = acc[m][n][r];
    }
  }
}

// ---------------- fp32 -> fp16 converts ----------------
__global__ __launch_bounds__(256) void cvt_kernel(const float* __restrict__ in,
                                                  u16* __restrict__ out, int n8) {
  const int i = blockIdx.x * 256 + threadIdx.x;
  if (i >= n8) return;
  const float4v a = *(const float4v*)(in + (size_t)i * 8);
  const float4v b = *(const float4v*)(in + (size_t)i * 8 + 4);
  ushort8 o;
  o[0] = f2h(a[0]); o[1] = f2h(a[1]); o[2] = f2h(a[2]); o[3] = f2h(a[3]);
  o[4] = f2h(b[0]); o[5] = f2h(b[1]); o[6] = f2h(b[2]); o[7] = f2h(b[3]);
  *(ushort8*)(out + (size_t)i * 8) = o;
}

__global__ __launch_bounds__(256) void cvt3_kernel(const float* __restrict__ w0,
                                                   const float* __restrict__ w1,
                                                   const float* __restrict__ w2,
                                                   u16* __restrict__ out, int n8) {
  const int i = blockIdx.x * 256 + threadIdx.x;
  if (i >= n8) return;
  const float* in = (blockIdx.y == 0) ? w0 : (blockIdx.y == 1) ? w1 : w2;
  u16* o_ = out + (size_t)blockIdx.y * D_ * D_;
  const float4v a = *(const float4v*)(in + (size_t)i * 8);
  const float4v b = *(const float4v*)(in + (size_t)i * 8 + 4);
  ushort8 o;
  o[0] = f2h(a[0]); o[1] = f2h(a[1]); o[2] = f2h(a[2]); o[3] = f2h(a[3]);
  o[4] = f2h(b[0]); o[5] = f2h(b[1]); o[6] = f2h(b[2]); o[7] = f2h(b[3]);
  *(ushort8*)(o_ + (size_t)i * 8) = o;
}

extern "C" void kernel_launch(void* const* d_in, const int* in_sizes, int n_in,
                              void* d_out, int out_size, void* d_ws, size_t ws_size,
                              hipStream_t stream) {
  (void)in_sizes; (void)n_in; (void)out_size;
  const float* x  = (const float*)d_in[0];
  const float* Wq = (const float*)d_in[1];
  const float* bq = (const float*)d_in[2];
  const float* Wk = (const float*)d_in[3];
  const float* bk = (const float*)d_in[4];
  const float* Wv = (const float*)d_in[5];
  const float* bv = (const float*)d_in[6];
  float* out = (float*)d_out;

  char* ws = (char*)d_ws;
  size_t off = 0;
  auto alloc = [&](size_t bytes) -> char* {
    char* p = ws + off;
    off += (bytes + 255) & ~(size_t)255;
    return p;
  };
  const size_t MS = (size_t)B_ * S_;  // 16384 rows total
  u16* xh = (u16*)alloc(MS * D_ * 2);
  u16* Wh = (u16*)alloc(3ull * D_ * D_ * 2);
  u16* Qb = (u16*)alloc(MS * D_ * 2);
  u16* Kb = (u16*)alloc(MS * D_ * 2);
  u16* Vt = (u16*)alloc(MS * D_ * 2);
  const size_t Efull = (size_t)B_ * S_ * S_ * 2;
  const bool full = ws_size >= off + Efull;  // ~136 MB total; else per-batch E
  u16* E = (u16*)alloc(full ? Efull : (size_t)S_ * S_ * 2);

  // fp32 -> fp16 converts
  {
    const int n8 = (int)(MS * D_ / 8);
    cvt_kernel<<<dim3((n8 + 255) / 256), dim3(256), 0, stream>>>(x, xh, n8);
    const int w8 = D_ * D_ / 8;
    cvt3_kernel<<<dim3((w8 + 255) / 256, 3), dim3(256), 0, stream>>>(Wq, Wk, Wv, Wh, w8);
  }

  // Q/K/V projections (z = 0/1/2), 256x256 tiles
  proj_kernel<<<dim3(D_ / 256, MS / 256, 3), dim3(512), 0, stream>>>(
      xh, Wh, bq, bk, bv, Qb, Kb, Vt);

  if (full) {
    qk_kernel<<<dim3(S_ / 256, S_ / 256, B_), dim3(512), 0, stream>>>(
        Qb, Kb, E, (size_t)S_ * D_, (size_t)S_ * S_);
    softmax_kernel<<<dim3(B_ * S_ / 4), dim3(256), 0, stream>>>(E);
    pv_kernel<<<dim3(D_ / 256, S_ / 128, B_), dim3(512), 0, stream>>>(
        E, Vt, out, (size_t)S_ * S_, (size_t)D_ * S_, (size_t)S_ * D_);
  } else {
    for (int b = 0; b < B_; ++b) {
      qk_kernel<<<dim3(S_ / 256, S_ / 256, 1), dim3(512), 0, stream>>>(
          Qb + (size_t)b * S_ * D_, Kb + (size_t)b * S_ * D_, E, 0, 0);
      softmax_kernel<<<dim3(S_ / 4), dim3(256), 0, stream>>>(E);
      pv_kernel<<<dim3(D_ / 256, S_ / 128, 1), dim3(512), 0, stream>>>(
          E, Vt + (size_t)b * D_ * S_, out + (size_t)b * S_ * D_, 0, 0, 0);
    }
  }
}

// Round 8
// 162.836 us; speedup vs baseline: 1.0106x; 1.0106x over previous
//
#include <hip/hip_runtime.h>

typedef unsigned short u16;
typedef _Float16 f16;

using half8   = __attribute__((ext_vector_type(8))) _Float16;
using f32x4   = __attribute__((ext_vector_type(4))) float;
using ushort8 = __attribute__((ext_vector_type(8))) unsigned short;
using us4     = __attribute__((ext_vector_type(4))) unsigned short;
using float4v = __attribute__((ext_vector_type(4))) float;

#define B_  8
#define S_  2048
#define D_  512

__device__ __forceinline__ u16 f2h(float f) {
  f16 h = (f16)f;
  u16 u;
  __builtin_memcpy(&u, &h, 2);
  return u;
}

__device__ __forceinline__ float h2f(u16 h) {
  f16 x;
  __builtin_memcpy(&x, &h, 2);
  return (float)x;
}

__device__ __forceinline__ void stage16(const void* g, void* l) {
  __builtin_amdgcn_global_load_lds((const __attribute__((address_space(1))) void*)g,
                                   (__attribute__((address_space(3))) void*)l,
                                   16, 0, 0);
}

// XCD-aware bijective remap (all grids have nwg % 8 == 0).
__device__ __forceinline__ void xcd_remap(int& bx, int& by, int& bz) {
  const int lin = ((int)blockIdx.z * (int)gridDim.y + (int)blockIdx.y) * (int)gridDim.x
                  + (int)blockIdx.x;
  const int nwg = (int)gridDim.x * (int)gridDim.y * (int)gridDim.z;
  const int swz = (lin & 7) * (nwg >> 3) + (lin >> 3);
  bx = swz % (int)gridDim.x;
  const int tmp = swz / (int)gridDim.x;
  by = tmp % (int)gridDim.y;
  bz = tmp / (int)gridDim.y;
}

// ===================== 8-phase GEMM core =====================
// C[BM x 256] = A[BM x K] * B[256 x K]^T, fp16 in, fp32 accum.
// BM = M_REP*32 (256 or 128). 512 threads = 8 waves (2 wave-rows x 4 wave-cols),
// per-wave output (M_REP*16) x 64. K-tile BK=64 = 2 k-step images of 32.
//
// LDS: 2 K-tile buffers (A: 2 images x BM x 32, B: 2 images x 256 x 32, fp16).
// Per-image paired-row swizzle (PMC-verified rounds 4-6): global (r, 8-col
// chunk g) -> image elem R*64 + ((((r&1)<<2)|g) ^ (R&7))*8, R = r>>1.
// gload_lds dest linear, global source pre-swizzled (both-sides rule).
//
// Schedule per K-tile t (reads buf[t&1]; stages tile t+2 into SAME buffer's
// dead regions; tile t+1 lives untouched in the other buffer):
//   P0: vmcnt(L)+barrier; read A-q0 + B-q0 frags; MFMA (mh0,nh0); barrier
//   P1: read B-q1; stage A-q0,B-q0 of t+2; barrier; MFMA (mh0,nh1); barrier
//   P2: read A-q1; stage B-q1;              barrier; MFMA (mh1,nh1); barrier
//   P3:            stage A-q1;              barrier; MFMA (mh1,nh0); barrier
// Region qX = rows r with (r & QS) == X*QS (QS = per-wave quadrant row span),
// matching exactly the rows ALL waves last read in the phase before staging.
// vmcnt(L) at P0 retires everything older than tile t+1's L loads => tile t
// complete; final K-tile uses vmcnt(0). MFMA clusters wrapped in s_setprio.
template<int M_REP>
__device__ __forceinline__ void core8p(const u16* __restrict__ A,
                                       const u16* __restrict__ B,
                                       int K, int m0, int n0,
                                       u16* lds, f32x4 acc[M_REP][4]) {
  constexpr int M2   = M_REP / 2;
  constexpr int BM   = M_REP * 32;
  constexpr int AIS  = BM * 32;        // A image stride (elems)
  constexpr int BOFF = BM * 64;        // B region base (elems)
  constexpr int BUFE = BM * 64 + 16384;
  constexpr int ASL  = BM / 128;       // A stage slots per quadrant (2 or 1)
  constexpr int L    = 2 * ASL + 4;    // gload_lds per wave per K-tile
  constexpr int QSRA = (BM == 256) ? 32 : 16;  // A region granularity (paired rows)

  const int tid  = threadIdx.x;
  const int lane = tid & 63;
  const int wave = tid >> 6;
  const int wr = wave >> 2, wc = wave & 3;
  const int fr = lane & 15, fgrp = lane >> 4;

  // ---- stage slot tables: wave-uniform LDS dest + per-lane global offset ----
  int    dstA[2][ASL];  size_t gA[2][ASL];
  int    dstB[2][2];    size_t gB[2][2];
  #pragma unroll
  for (int q = 0; q < 2; ++q) {
    #pragma unroll
    for (int s = 0; s < ASL; ++s) {
      int ks, jr;
      if constexpr (ASL == 2) { ks = s; jr = wave * 8; }
      else                    { ks = wave >> 2; jr = (wave & 3) * 8; }
      const int R   = (jr / QSRA) * (2 * QSRA) + q * QSRA + (jr % QSRA);
      const int dst = ks * AIS + R * 64;
      dstA[q][s] = dst;
      const int e   = dst + lane * 8;
      const int ks2 = e / AIS, le = e - ks2 * AIS;
      const int RR  = le >> 6;
      const int s0  = ((le >> 3) & 7) ^ (RR & 7);
      gA[q][s] = (size_t)(m0 + 2 * RR + (s0 >> 2)) * K + ks2 * 32 + (s0 & 3) * 8;
    }
    #pragma unroll
    for (int s = 0; s < 2; ++s) {
      const int jr  = wave * 8;
      const int R   = (jr / 16) * 32 + q * 16 + (jr % 16);
      const int dst = BOFF + s * 8192 + R * 64;
      dstB[q][s] = dst;
      const int e   = dst - BOFF + lane * 8;
      const int ks2 = e / 8192, le = e - ks2 * 8192;
      const int RR  = le >> 6;
      const int s0  = ((le >> 3) & 7) ^ (RR & 7);
      gB[q][s] = (size_t)(n0 + 2 * RR + (s0 >> 2)) * K + ks2 * 32 + (s0 & 3) * 8;
    }
  }

  // ---- fragment read byte offsets ----
  int offA[2][M2][2], offB[2][2][2];
  #pragma unroll
  for (int mh = 0; mh < 2; ++mh)
    #pragma unroll
    for (int m = 0; m < M2; ++m)
      #pragma unroll
      for (int ks = 0; ks < 2; ++ks) {
        const int ra = wr * (M_REP * 16) + (mh * M2 + m) * 16 + fr;
        const int Ra = ra >> 1;
        offA[mh][m][ks] = (ks * AIS + Ra * 64) * 2 +
                          (((((ra & 1) << 2) | fgrp) ^ (Ra & 7)) << 4);
      }
  #pragma unroll
  for (int nh = 0; nh < 2; ++nh)
    #pragma unroll
    for (int n = 0; n < 2; ++n)
      #pragma unroll
      for (int ks = 0; ks < 2; ++ks) {
        const int rb = wc * 64 + (nh * 2 + n) * 16 + fr;
        const int Rb = rb >> 1;
        offB[nh][n][ks] = (BOFF + ks * 8192 + Rb * 64) * 2 +
                          (((((rb & 1) << 2) | fgrp) ^ (Rb & 7)) << 4);
      }

  const f32x4 vzero = {0.f, 0.f, 0.f, 0.f};
  #pragma unroll
  for (int m = 0; m < M_REP; ++m)
    #pragma unroll
    for (int n = 0; n < 4; ++n)
      acc[m][n] = vzero;

  const int NT = K >> 6;

  auto stageA = [&](int q, int tt) {
    u16* bb = lds + (tt & 1) * BUFE;
    #pragma unroll
    for (int s = 0; s < ASL; ++s)
      stage16(A + gA[q][s] + (size_t)tt * 64, bb + dstA[q][s]);
  };
  auto stageB = [&](int q, int tt) {
    u16* bb = lds + (tt & 1) * BUFE;
    #pragma unroll
    for (int s = 0; s < 2; ++s)
      stage16(B + gB[q][s] + (size_t)tt * 64, bb + dstB[q][s]);
  };

  // prologue: tiles 0 and 1 fully staged (issue order = steady-state order)
  stageA(0, 0); stageB(0, 0); stageB(1, 0); stageA(1, 0);
  stageA(0, 1); stageB(0, 1); stageB(1, 1); stageA(1, 1);

  half8 a[M2][2], blo[2][2], bhi[2][2];

#define MFMA_Q(MH, BB, NB)                                                       \
  __builtin_amdgcn_s_setprio(1);                                                 \
  _Pragma("unroll")                                                              \
  for (int m = 0; m < M2; ++m)                                                   \
    _Pragma("unroll")                                                            \
    for (int n = 0; n < 2; ++n)                                                  \
      _Pragma("unroll")                                                          \
      for (int ks = 0; ks < 2; ++ks)                                             \
        acc[(MH) * M2 + m][(NB) + n] = __builtin_amdgcn_mfma_f32_16x16x32_f16(   \
            a[m][ks], BB[n][ks], acc[(MH) * M2 + m][(NB) + n], 0, 0, 0);         \
  __builtin_amdgcn_s_setprio(0);

  for (int t = 0; t < NT; ++t) {
    const char* rb_ = (const char*)(lds + (t & 1) * BUFE);
    const int tt = t + 2;
    const bool st = (tt < NT);

    // ---- P0 ----
    if (t == NT - 1) asm volatile("s_waitcnt vmcnt(0)\n\ts_barrier" ::: "memory");
    else if constexpr (L == 8) asm volatile("s_waitcnt vmcnt(8)\n\ts_barrier" ::: "memory");
    else                       asm volatile("s_waitcnt vmcnt(6)\n\ts_barrier" ::: "memory");
    #pragma unroll
    for (int m = 0; m < M2; ++m)
      #pragma unroll
      for (int ks = 0; ks < 2; ++ks)
        a[m][ks] = *(const half8*)(rb_ + offA[0][m][ks]);
    #pragma unroll
    for (int n = 0; n < 2; ++n)
      #pragma unroll
      for (int ks = 0; ks < 2; ++ks)
        blo[n][ks] = *(const half8*)(rb_ + offB[0][n][ks]);
    MFMA_Q(0, blo, 0)
    asm volatile("s_barrier" ::: "memory");

    // ---- P1 ----
    #pragma unroll
    for (int n = 0; n < 2; ++n)
      #pragma unroll
      for (int ks = 0; ks < 2; ++ks)
        bhi[n][ks] = *(const half8*)(rb_ + offB[1][n][ks]);
    if (st) { stageA(0, tt); stageB(0, tt); }
    asm volatile("s_barrier" ::: "memory");
    MFMA_Q(0, bhi, 2)
    asm volatile("s_barrier" ::: "memory");

    // ---- P2 ----
    #pragma unroll
    for (int m = 0; m < M2; ++m)
      #pragma unroll
      for (int ks = 0; ks < 2; ++ks)
        a[m][ks] = *(const half8*)(rb_ + offA[1][m][ks]);
    if (st) stageB(1, tt);
    asm volatile("s_barrier" ::: "memory");
    MFMA_Q(1, bhi, 2)
    asm volatile("s_barrier" ::: "memory");

    // ---- P3 ----
    if (st) stageA(1, tt);
    asm volatile("s_barrier" ::: "memory");
    MFMA_Q(1, blo, 0)
    asm volatile("s_barrier" ::: "memory");
  }
#undef MFMA_Q
}

// ---------------- projections (128x256): Q/K fp16 store, V transposed [b][d][s] ----------------
__global__ __launch_bounds__(512, 1) void proj_kernel(
    const u16* __restrict__ xh, const u16* __restrict__ Wh,
    const float* __restrict__ bq, const float* __restrict__ bk, const float* __restrict__ bv,
    u16* __restrict__ Qb, u16* __restrict__ Kb, u16* __restrict__ Vt) {
  __shared__ __align__(16) u16 lds[2 * (128 * 64 + 16384)];  // 96 KB
  int bx, by, bz;
  xcd_remap(bx, by, bz);
  const int z  = bz;
  const int m0 = by * 128;
  const int n0 = bx * 256;
  const u16* W = Wh + (size_t)z * D_ * D_;
  const float* bias = (z == 0) ? bq : (z == 1) ? bk : bv;
  f32x4 acc[4][4];
  core8p<4>(xh, W, D_, m0, n0, lds, acc);

  const int lane = threadIdx.x & 63;
  const int wave = threadIdx.x >> 6;
  const int wr = wave >> 2, wc = wave & 3;
  #pragma unroll
  for (int m = 0; m < 4; ++m) {
    const int gr0 = m0 + wr * 64 + m * 16 + ((lane >> 4) << 2);
    #pragma unroll
    for (int n = 0; n < 4; ++n) {
      const int gc = n0 + wc * 64 + n * 16 + (lane & 15);
      const float bb = bias[gc];
      if (z < 2) {
        u16* O = z ? Kb : Qb;
        #pragma unroll
        for (int r = 0; r < 4; ++r)
          O[(size_t)(gr0 + r) * D_ + gc] = f2h(acc[m][n][r] + bb);
      } else {
        const int bidx = gr0 >> 11;      // 2048 rows/batch; 128-row tiles never straddle
        const int s    = gr0 & 2047;
        us4 p;
        #pragma unroll
        for (int r = 0; r < 4; ++r) p[r] = f2h(acc[m][n][r] + bb);
        *(us4*)(Vt + ((size_t)bidx * D_ + gc) * S_ + s) = p;
      }
    }
  }
}

// ---------------- QK^T (256x256) -> E fp16 ----------------
__global__ __launch_bounds__(512, 1) void qk_kernel(
    const u16* __restrict__ Qb, const u16* __restrict__ Kb, u16* __restrict__ E,
    size_t sA, size_t sE) {
  __shared__ __align__(16) u16 lds[2 * (256 * 64 + 16384)];  // 128 KB
  int bx, by, bz;
  xcd_remap(bx, by, bz);
  const int z  = bz;
  const int m0 = by * 256;
  const int n0 = bx * 256;
  f32x4 acc[8][4];
  core8p<8>(Qb + (size_t)z * sA, Kb + (size_t)z * sA, D_, m0, n0, lds, acc);

  u16* Eb = E + (size_t)z * sE;
  const int lane = threadIdx.x & 63;
  const int wave = threadIdx.x >> 6;
  const int wr = wave >> 2, wc = wave & 3;
  #pragma unroll
  for (int m = 0; m < 8; ++m) {
    const int gr0 = m0 + wr * 128 + m * 16 + ((lane >> 4) << 2);
    #pragma unroll
    for (int n = 0; n < 4; ++n) {
      const int gc = n0 + wc * 64 + n * 16 + (lane & 15);
      #pragma unroll
      for (int r = 0; r < 4; ++r)
        Eb[(size_t)(gr0 + r) * S_ + gc] = f2h(acc[m][n][r]);
    }
  }
}

// ---------------- row softmax, in place fp16 -> fp16 ----------------
__global__ __launch_bounds__(256) void softmax_kernel(u16* __restrict__ E) {
  const int row  = blockIdx.x * 4 + (threadIdx.x >> 6);
  const int lane = threadIdx.x & 63;
  u16* R = E + (size_t)row * S_;
  float e[32];
  #pragma unroll
  for (int i = 0; i < 4; ++i) {
    ushort8 v = *(const ushort8*)(R + i * 512 + lane * 8);
    #pragma unroll
    for (int j = 0; j < 8; ++j) e[i * 8 + j] = h2f(v[j]);
  }
  float m = e[0];
  #pragma unroll
  for (int i = 1; i < 32; ++i) m = fmaxf(m, e[i]);
  for (int off = 32; off > 0; off >>= 1) m = fmaxf(m, __shfl_xor(m, off, 64));
  float s = 0.f;
  #pragma unroll
  for (int i = 0; i < 32; ++i) { e[i] = __expf(e[i] - m); s += e[i]; }
  for (int off = 32; off > 0; off >>= 1) s += __shfl_xor(s, off, 64);
  const float inv = 1.f / s;
  #pragma unroll
  for (int i = 0; i < 4; ++i) {
    ushort8 v;
    #pragma unroll
    for (int j = 0; j < 8; ++j) v[j] = f2h(e[i * 8 + j] * inv);
    *(ushort8*)(R + i * 512 + lane * 8) = v;
  }
}

// ---------------- PV (128x256) -> fp32 out ----------------
__global__ __launch_bounds__(512, 1) void pv_kernel(
    const u16* __restrict__ P, const u16* __restrict__ Vt, float* __restrict__ out,
    size_t sP, size_t sV, size_t sO) {
  __shared__ __align__(16) u16 lds[2 * (128 * 64 + 16384)];  // 96 KB
  int bx, by, bz;
  xcd_remap(bx, by, bz);
  const int z  = bz;
  const int m0 = by * 128;
  const int n0 = bx * 256;
  f32x4 acc[4][4];
  core8p<4>(P + (size_t)z * sP, Vt + (size_t)z * sV, S_, m0, n0, lds, acc);

  float* Ob = out + (size_t)z * sO;
  const int lane = threadIdx.x & 63;
  const int wave = threadIdx.x >> 6;
  const int wr = wave >> 2, wc = wave & 3;
  #pragma unroll
  for (int m = 0; m < 4; ++m) {
    const int gr0 = m0 + wr * 64 + m * 16 + ((lane >> 4) << 2);
    #pragma unroll
    for (int n = 0; n < 4; ++n) {
      const int gc = n0 + wc * 64 + n * 16 + (lane & 15);
      #pragma unroll
      for (int r = 0; r < 4; ++r)
        Ob[(size_t)(gr0 + r) * D_ + gc] = acc[m][n][r];
    }
  }
}

// ---------------- fp32 -> fp16 converts ----------------
__global__ __launch_bounds__(256) void cvt_kernel(const float* __restrict__ in,
                                                  u16* __restrict__ out, int n8) {
  const int i = blockIdx.x * 256 + threadIdx.x;
  if (i >= n8) return;
  const float4v a = *(const float4v*)(in + (size_t)i * 8);
  const float4v b = *(const float4v*)(in + (size_t)i * 8 + 4);
  ushort8 o;
  o[0] = f2h(a[0]); o[1] = f2h(a[1]); o[2] = f2h(a[2]); o[3] = f2h(a[3]);
  o[4] = f2h(b[0]); o[5] = f2h(b[1]); o[6] = f2h(b[2]); o[7] = f2h(b[3]);
  *(ushort8*)(out + (size_t)i * 8) = o;
}

__global__ __launch_bounds__(256) void cvt3_kernel(const float* __restrict__ w0,
                                                   const float* __restrict__ w1,
                                                   const float* __restrict__ w2,
                                                   u16* __restrict__ out, int n8) {
  const int i = blockIdx.x * 256 + threadIdx.x;
  if (i >= n8) return;
  const float* in = (blockIdx.y == 0) ? w0 : (blockIdx.y == 1) ? w1 : w2;
  u16* o_ = out + (size_t)blockIdx.y * D_ * D_;
  const float4v a = *(const float4v*)(in + (size_t)i * 8);
  const float4v b = *(const float4v*)(in + (size_t)i * 8 + 4);
  ushort8 o;
  o[0] = f2h(a[0]); o[1] = f2h(a[1]); o[2] = f2h(a[2]); o[3] = f2h(a[3]);
  o[4] = f2h(b[0]); o[5] = f2h(b[1]); o[6] = f2h(b[2]); o[7] = f2h(b[3]);
  *(ushort8*)(o_ + (size_t)i * 8) = o;
}

extern "C" void kernel_launch(void* const* d_in, const int* in_sizes, int n_in,
                              void* d_out, int out_size, void* d_ws, size_t ws_size,
                              hipStream_t stream) {
  (void)in_sizes; (void)n_in; (void)out_size;
  const float* x  = (const float*)d_in[0];
  const float* Wq = (const float*)d_in[1];
  const float* bq = (const float*)d_in[2];
  const float* Wk = (const float*)d_in[3];
  const float* bk = (const float*)d_in[4];
  const float* Wv = (const float*)d_in[5];
  const float* bv = (const float*)d_in[6];
  float* out = (float*)d_out;

  char* ws = (char*)d_ws;
  size_t off = 0;
  auto alloc = [&](size_t bytes) -> char* {
    char* p = ws + off;
    off += (bytes + 255) & ~(size_t)255;
    return p;
  };
  const size_t MS = (size_t)B_ * S_;  // 16384 rows total
  u16* xh = (u16*)alloc(MS * D_ * 2);
  u16* Wh = (u16*)alloc(3ull * D_ * D_ * 2);
  u16* Qb = (u16*)alloc(MS * D_ * 2);
  u16* Kb = (u16*)alloc(MS * D_ * 2);
  u16* Vt = (u16*)alloc(MS * D_ * 2);
  const size_t Efull = (size_t)B_ * S_ * S_ * 2;
  const bool full = ws_size >= off + Efull;  // ~136 MB total; else per-batch E
  u16* E = (u16*)alloc(full ? Efull : (size_t)S_ * S_ * 2);

  // fp32 -> fp16 converts
  {
    const int n8 = (int)(MS * D_ / 8);
    cvt_kernel<<<dim3((n8 + 255) / 256), dim3(256), 0, stream>>>(x, xh, n8);
    const int w8 = D_ * D_ / 8;
    cvt3_kernel<<<dim3((w8 + 255) / 256, 3), dim3(256), 0, stream>>>(Wq, Wk, Wv, Wh, w8);
  }

  // Q/K/V projections (z = 0/1/2), 128x256 tiles
  proj_kernel<<<dim3(D_ / 256, MS / 128, 3), dim3(512), 0, stream>>>(
      xh, Wh, bq, bk, bv, Qb, Kb, Vt);

  if (full) {
    qk_kernel<<<dim3(S_ / 256, S_ / 256, B_), dim3(512), 0, stream>>>(
        Qb, Kb, E, (size_t)S_ * D_, (size_t)S_ * S_);
    softmax_kernel<<<dim3(B_ * S_ / 4), dim3(256), 0, stream>>>(E);
    pv_kernel<<<dim3(D_ / 256, S_ / 128, B_), dim3(512), 0, stream>>>(
        E, Vt, out, (size_t)S_ * S_, (size_t)D_ * S_, (size_t)S_ * D_);
  } else {
    for (int b = 0; b < B_; ++b) {
      qk_kernel<<<dim3(S_ / 256, S_ / 256, 1), dim3(512), 0, stream>>>(
          Qb + (size_t)b * S_ * D_, Kb + (size_t)b * S_ * D_, E, 0, 0);
      softmax_kernel<<<dim3(S_ / 4), dim3(256), 0, stream>>>(E);
      pv_kernel<<<dim3(D_ / 256, S_ / 128, 1), dim3(512), 0, stream>>>(
          E, Vt + (size_t)b * D_ * S_, out + (size_t)b * S_ * D_, 0, 0, 0);
    }
  }
}